// Round 12
// baseline (265.054 us; speedup 1.0000x reference)
//
#include <hip/hip_runtime.h>

typedef float f32x4 __attribute__((ext_vector_type(4)));
typedef short short8 __attribute__((ext_vector_type(8)));
typedef unsigned int u32;
typedef unsigned short u16;

#define CLL 0.25f                     // landmark self/neighbor coeff (deg=4)
#define CML 0.06019292654288460f      // 0.5/sqrt(69)
#define SELFM 0.014492753623188406f   // 1/69

__device__ __forceinline__ u16 f2bf(float x) {
  u32 b = __float_as_uint(x);
  return (u16)((b + 0x7FFFu + ((b >> 16) & 1u)) >> 16);
}
__device__ __forceinline__ u32 cvtpk(float a, float b) {
  u32 r;
  asm("v_cvt_pk_bf16_f32 %0, %1, %2" : "=v"(r) : "v"(a), "v"(b));
  return r;
}

// prep: (a) swizzle 7 HIDxHID weight mats into bf16 MFMA B-fragments;
//       (b) fold BN into per-layer affine sc/sh.  (R6-proven)
__global__ void prep(const float* __restrict__ midW, const float* __restrict__ lastW,
                     const float* __restrict__ bng, const float* __restrict__ bnb,
                     const float* __restrict__ bnm, const float* __restrict__ bnv,
                     u16* __restrict__ frag, float* __restrict__ bns) {
  const int t0 = blockIdx.x * blockDim.x + threadIdx.x;
  for (int u = t0; u < 7 * 4 * 2 * 64; u += gridDim.x * blockDim.x) {
    const int lane = u & 63;
    const int t = u >> 6;
    const int ks = t & 1;
    const int nt = (t >> 1) & 3;
    const int l = t >> 3;  // 0..6 -> layers 1..7
    const float* W = (l < 6) ? (midW + l * 4096) : lastW;
    const int col = nt * 16 + (lane & 15);
    const int kb = ks * 32 + (lane >> 4) * 8;
    u16* dst = frag + (size_t)u * 8;
#pragma unroll
    for (int j = 0; j < 8; ++j) dst[j] = f2bf(W[(kb + j) * 64 + col]);
  }
  for (int u = t0; u < 7 * 64; u += gridDim.x * blockDim.x) {
    const int l = u >> 6, f = u & 63;
    const float sc = (float)((double)bng[l * 64 + f] / sqrt((double)bnv[l * 64 + f] + 1e-5));
    bns[l * 128 + f] = sc;
    bns[l * 128 + 64 + f] = bnb[l * 64 + f] - bnm[l * 64 + f] * sc;
  }
}

#define SUM4(V) ((V)[0] + (V)[1] + (V)[2] + (V)[3])
#define MAX4(V) fmaxf(fmaxf((V)[0], (V)[1]), fmaxf((V)[2], (V)[3]))
#define MM(A, B, C) __builtin_amdgcn_mfma_f32_16x16x32_bf16(A, B, C, 0, 0, 0)

// ring stencil, 2 col-sets, boundary values bf16-packed through one shfl (R10-proven)
#define STEP2(MT, TA, TPA, TNA, TB, TPB, TNB, HA, HB, RESID)           \
  {                                                                    \
    const float spA_ = (qg == 3) ? TPA[3] : TA[3];                     \
    const float spB_ = (qg == 3) ? TPB[3] : TB[3];                     \
    const u32 pvP_ = (u32)__shfl((int)cvtpk(spA_, spB_), (lane + 48) & 63, 64); \
    const float snA_ = (qg == 0) ? TNA[0] : TA[0];                     \
    const float snB_ = (qg == 0) ? TNB[0] : TB[0];                     \
    const u32 nvP_ = (u32)__shfl((int)cvtpk(snA_, snB_), (lane + 16) & 63, 64); \
    const float pvA_ = __uint_as_float(pvP_ << 16);                    \
    const float pvB_ = __uint_as_float(pvP_ & 0xffff0000u);            \
    const float nvA_ = __uint_as_float(nvP_ << 16);                    \
    const float nvB_ = __uint_as_float(nvP_ & 0xffff0000u);            \
    const float ta0A_ = ((MT) == 0 && qg == 0) ? tA4[3] : pvA_;        \
    const float ta0B_ = ((MT) == 0 && qg == 0) ? tB4[3] : pvB_;        \
    const float tb3A_ = ((MT) == 4 && qg == 0) ? tA0[0] : nvA_;        \
    const float tb3B_ = ((MT) == 4 && qg == 0) ? tB0[0] : nvB_;        \
    float oA0 = fmaf(CLL, ta0A_ + TA[0] + TA[1], cmtA_);               \
    float oA1 = fmaf(CLL, TA[0] + TA[1] + TA[2], cmtA_);               \
    float oA2 = fmaf(CLL, TA[1] + TA[2] + TA[3], cmtA_);               \
    float oA3 = fmaf(CLL, TA[2] + TA[3] + tb3A_, cmtA_);               \
    float oB0 = fmaf(CLL, ta0B_ + TB[0] + TB[1], cmtB_);               \
    float oB1 = fmaf(CLL, TB[0] + TB[1] + TB[2], cmtB_);               \
    float oB2 = fmaf(CLL, TB[1] + TB[2] + TB[3], cmtB_);               \
    float oB3 = fmaf(CLL, TB[2] + TB[3] + tb3B_, cmtB_);               \
    oA0 = fmaf(fmaxf(oA0, 0.f), scA_, shA_);                           \
    oA1 = fmaf(fmaxf(oA1, 0.f), scA_, shA_);                           \
    oA2 = fmaf(fmaxf(oA2, 0.f), scA_, shA_);                           \
    oA3 = fmaf(fmaxf(oA3, 0.f), scA_, shA_);                           \
    oB0 = fmaf(fmaxf(oB0, 0.f), scB_, shB_);                           \
    oB1 = fmaf(fmaxf(oB1, 0.f), scB_, shB_);                           \
    oB2 = fmaf(fmaxf(oB2, 0.f), scB_, shB_);                           \
    oB3 = fmaf(fmaxf(oB3, 0.f), scB_, shB_);                           \
    if (RESID) {                                                      \
      oA0 += HA[0]; oA1 += HA[1]; oA2 += HA[2]; oA3 += HA[3];          \
      oB0 += HB[0]; oB1 += HB[1]; oB2 += HB[2]; oB3 += HB[3];          \
    }                                                                  \
    HA[0] = oA0; HA[1] = oA1; HA[2] = oA2; HA[3] = oA3;                \
    HB[0] = oB0; HB[1] = oB1; HB[2] = oB2; HB[3] = oB3;                \
  }

// bf16 h write into swizzled hb for one col (4 scattered b16 stores)
#define WPAIR2(HW, MT, H, CQ)                                          \
  {                                                                    \
    const u32 pa = cvtpk(H[0], H[1]);                                  \
    const u32 pb = cvtpk(H[2], H[3]);                                  \
    (HW)[(16 * (MT) + 4 * qg + 0) * 64 + (CQ)] = (u16)pa;              \
    (HW)[(16 * (MT) + 4 * qg + 1) * 64 + ((CQ) ^ 8)] = (u16)(pa >> 16);\
    (HW)[(16 * (MT) + 4 * qg + 2) * 64 + ((CQ) ^ 16)] = (u16)pb;       \
    (HW)[(16 * (MT) + 4 * qg + 3) * 64 + ((CQ) ^ 24)] = (u16)(pb >> 16); \
  }

// epilogue for one col-set pair (h regs + col ids parameterized)
#define EPILOG2(HA0, HA1, HA2, HA3, HA4, HB0, HB1, HB2, HB3, HB4,      \
                CQA_, CQB_, CA_, CB_, RESID, WRITE, BA, BB, SCA, SHA, SCB, SHB) \
  {                                                                    \
    float SA_ = SUM4(tA0) + SUM4(tA1) + SUM4(tA2) + SUM4(tA3) + SUM4(tA4); \
    float SB_ = SUM4(tB0) + SUM4(tB1) + SUM4(tB2) + SUM4(tB3) + SUM4(tB4); \
    if (qg == 1) { SA_ -= tA4[0]; SB_ -= tB4[0]; }                     \
    SA_ += __shfl_xor(SA_, 16, 64); SA_ += __shfl_xor(SA_, 32, 64);    \
    SB_ += __shfl_xor(SB_, 16, 64); SB_ += __shfl_xor(SB_, 32, 64);    \
    const u32 pk_ = (u32)__shfl((int)cvtpk(tA4[0], tB4[0]), 16 + p15, 64); \
    const float scA_ = (SCA), shA_ = (SHA), scB_ = (SCB), shB_ = (SHB);\
    const float cmtA_ = fmaf(CML, __uint_as_float(pk_ << 16), (BA));   \
    const float cmtB_ = fmaf(CML, __uint_as_float(pk_ & 0xffff0000u), (BB)); \
    float mvA_ = 0.f, mvB_ = 0.f;                                      \
    if (qg == 1) {                                                     \
      mvA_ = fmaf(fmaxf(fmaf(CML, SA_, fmaf(SELFM, tA4[0], (BA))), 0.f), scA_, shA_); \
      mvB_ = fmaf(fmaxf(fmaf(CML, SB_, fmaf(SELFM, tB4[0], (BB))), 0.f), scB_, shB_); \
      if (RESID) { mvA_ += HA4[0]; mvB_ += HB4[0]; }                   \
    }                                                                  \
    STEP2(0, tA0, tA4, tA1, tB0, tB4, tB1, HA0, HB0, RESID)            \
    STEP2(1, tA1, tA0, tA2, tB1, tB0, tB2, HA1, HB1, RESID)            \
    STEP2(2, tA2, tA1, tA3, tB2, tB1, tB3, HA2, HB2, RESID)            \
    STEP2(3, tA3, tA2, tA4, tB3, tB2, tB4, HA3, HB3, RESID)            \
    STEP2(4, tA4, tA3, tA0, tB4, tB3, tB0, HA4, HB4, RESID)            \
    if (qg == 1) { HA4[0] = mvA_; HB4[0] = mvB_; }                     \
    if (WRITE) {                                                       \
      WPAIR2(hb, 0, HA0, CQA_) WPAIR2(hb, 0, HB0, CQB_)                \
      WPAIR2(hb, 1, HA1, CQA_) WPAIR2(hb, 1, HB1, CQB_)                \
      WPAIR2(hb, 2, HA2, CQA_) WPAIR2(hb, 2, HB2, CQB_)                \
      WPAIR2(hb, 3, HA3, CQA_) WPAIR2(hb, 3, HB3, CQB_)                \
      if (qg == 0) { WPAIR2(hb, 4, HA4, CQA_) WPAIR2(hb, 4, HB4, CQB_) } \
      else if (qg == 1) {                                              \
        hb[68 * 64 + ((CA_) ^ 32)] = (u16)cvtpk(mvA_, mvA_);           \
        hb[68 * 64 + ((CB_) ^ 32)] = (u16)cvtpk(mvB_, mvB_);           \
      }                                                                \
    }                                                                  \
  }

// read ALL 10 A-fragments for this layer (before any store -> single buffer OK)
#define RD_A()                                                         \
  qa0 = *(const short8*)&hb[0 * 1024 + ra0]; qb0 = *(const short8*)&hb[0 * 1024 + ra1]; \
  qa1 = *(const short8*)&hb[1 * 1024 + ra0]; qb1 = *(const short8*)&hb[1 * 1024 + ra1]; \
  qa2 = *(const short8*)&hb[2 * 1024 + ra0]; qb2 = *(const short8*)&hb[2 * 1024 + ra1]; \
  qa3 = *(const short8*)&hb[3 * 1024 + ra0]; qb3 = *(const short8*)&hb[3 * 1024 + ra1]; \
  qa4 = *(const short8*)&hb[4 * 1024 + ra0]; qb4 = *(const short8*)&hb[4 * 1024 + ra1];

// load B-fragments for one pair of N-tiles from the global frag table
#define LDB(LF, NT0, NT1)                                              \
  {                                                                    \
    const u16* fa_ = frag + (((size_t)(LF) * 4 + (NT0)) * 2 * 64 + lane) * 8; \
    const u16* fb_ = frag + (((size_t)(LF) * 4 + (NT1)) * 2 * 64 + lane) * 8; \
    bA0 = *(const short8*)fa_; bA1 = *(const short8*)(fa_ + 512);      \
    bB0 = *(const short8*)fb_; bB1 = *(const short8*)(fb_ + 512);      \
  }

#define MPX(QA, QB, TA, TB)                                            \
  {                                                                    \
    f32x4 uA_ = z4, uB_ = z4;                                          \
    uA_ = MM(QA, bA0, uA_); uA_ = MM(QB, bA1, uA_);                    \
    uB_ = MM(QA, bB0, uB_); uB_ = MM(QB, bB1, uB_);                    \
    TA = uA_; TB = uB_;                                                \
  }

#define MFMA_PAIR() \
  MPX(qa0, qb0, tA0, tB0) MPX(qa1, qb1, tA1, tB1) MPX(qa2, qb2, tA2, tB2) \
  MPX(qa3, qb3, tA3, tB3) MPX(qa4, qb4, tA4, tB4)

// per-colset readout from registers
#define RDOUT(H0, H1, H2, H3, H4, C_)                                  \
  {                                                                    \
    float s_ = SUM4(H0) + SUM4(H1) + SUM4(H2) + SUM4(H3);              \
    float m_ = fmaxf(fmaxf(MAX4(H0), MAX4(H1)), fmaxf(MAX4(H2), MAX4(H3))); \
    if (qg == 0) { s_ += SUM4(H4); m_ = fmaxf(m_, MAX4(H4)); }         \
    s_ += __shfl_xor(s_, 16, 64); s_ += __shfl_xor(s_, 32, 64);        \
    m_ = fmaxf(m_, __shfl_xor(m_, 16, 64));                            \
    m_ = fmaxf(m_, __shfl_xor(m_, 32, 64));                            \
    if (qg == 0) { gv[C_] = s_ * (1.f / 68.f); gv[64 + C_] = m_; }     \
    if (qg == 1) mrow[C_] = H4[0];                                     \
  }

__launch_bounds__(256)
__global__ void gcn_fused(
    const float* __restrict__ x,
    const float* __restrict__ cfW, const float* __restrict__ cfb,
    const float* __restrict__ cmb, const float* __restrict__ clb,
    const float* __restrict__ aW1, const float* __restrict__ ab1,
    const float* __restrict__ aW2, const float* __restrict__ ab2,
    const float* __restrict__ f1W, const float* __restrict__ f1b,
    const float* __restrict__ f2W, const float* __restrict__ f2b,
    const u16* __restrict__ frag, const float* __restrict__ bns,
    float* __restrict__ out, int ngraphs) {
  // Per-wave LDS slices; NO cross-wave communication, NO barriers anywhere.
  __shared__ u16 hbAll[4][80 * 64];   // 40960 B: bf16 h, single buffer (in-order DS)
  __shared__ float xlAll[4][80 * 4];  // 5120 B: staged x, rows 69..79 = 0
  __shared__ float mrowAll[4][64];    // 1024 B
  __shared__ float gvAll[4][192];     // 3072 B   (total 50176 B/block)

  const int lane = threadIdx.x & 63;
  const int w = threadIdx.x >> 6;
  const int g = blockIdx.x * 4 + w;   // one wave = one graph
  if (g >= ngraphs) return;           // safe: no barriers in this kernel

  u16* hb = hbAll[w];
  float* xl4 = xlAll[w];
  float* mrow = mrowAll[w];
  float* gv = gvAll[w];

  const int p15 = lane & 15;
  const int qg = lane >> 4;
  const int cA = p15, cB = p15 + 16, cC = p15 + 32, cD = p15 + 48;
  const f32x4 z4 = {0.f, 0.f, 0.f, 0.f};

  // A-frag read addrs (XOR-swizzled hb; R6/R10-proven conflict-free)
  const int rsw = (p15 & 7) << 3;
  const int ra0 = (p15 * 64 + qg * 8) ^ rsw;
  const int ra1 = (p15 * 64 + 32 + qg * 8) ^ rsw;
  // write swizzle bases
  const int cqA = cA ^ ((qg & 1) << 5);
  const int cqB = cqA ^ 16;
  const int cqC = cqA ^ 32;
  const int cqD = cqA ^ 48;

  // zero pad rows 69..79 (stores never touch them; single buffer keeps them 0)
  for (int i = lane; i < 352; i += 64) ((u32*)hb)[2208 + i] = 0u;
  // stage x
  *(f32x4*)&xl4[lane * 4] = *(const f32x4*)&x[((size_t)g * 69 + lane) * 4];
  if (lane < 5)
    *(f32x4*)&xl4[(64 + lane) * 4] = *(const f32x4*)&x[((size_t)g * 69 + 64 + lane) * 4];
  else if (lane < 16)
    *(f32x4*)&xl4[(64 + lane) * 4] = z4;

  f32x4 tA0, tA1, tA2, tA3, tA4, tB0, tB1, tB2, tB3, tB4;
  f32x4 hA0, hA1, hA2, hA3, hA4, hB0, hB1, hB2, hB3, hB4;
  f32x4 hC0, hC1, hC2, hC3, hC4, hD0, hD1, hD2, hD3, hD4;
  short8 qa0, qa1, qa2, qa3, qa4, qb0, qb1, qb2, qb3, qb4;
  short8 bA0, bA1, bB0, bB1;

  // ---- layer 0: t = x @ W_first (exact fp32, K=4), per pair
#define L0T(MT, TA, TB, W0A, W1A, W2A, W3A, W0B, W1B, W2B, W3B)        \
  { _Pragma("unroll") for (int r = 0; r < 4; ++r) {                    \
      const f32x4 xv = *(const f32x4*)&xl4[(16 * (MT) + 4 * qg + r) * 4]; \
      TA[r] = fmaf(xv[0], W0A, fmaf(xv[1], W1A, fmaf(xv[2], W2A, xv[3] * W3A))); \
      TB[r] = fmaf(xv[0], W0B, fmaf(xv[1], W1B, fmaf(xv[2], W2B, xv[3] * W3B))); } }
  {
    const float a0 = cfW[cA], a1 = cfW[64 + cA], a2 = cfW[128 + cA], a3 = cfW[192 + cA];
    const float b0 = cfW[cB], b1 = cfW[64 + cB], b2 = cfW[128 + cB], b3 = cfW[192 + cB];
    L0T(0, tA0, tB0, a0, a1, a2, a3, b0, b1, b2, b3)
    L0T(1, tA1, tB1, a0, a1, a2, a3, b0, b1, b2, b3)
    L0T(2, tA2, tB2, a0, a1, a2, a3, b0, b1, b2, b3)
    L0T(3, tA3, tB3, a0, a1, a2, a3, b0, b1, b2, b3)
    L0T(4, tA4, tB4, a0, a1, a2, a3, b0, b1, b2, b3)
    EPILOG2(hA0, hA1, hA2, hA3, hA4, hB0, hB1, hB2, hB3, hB4, cqA, cqB, cA, cB,
            false, true, cfb[cA], cfb[cB], bns[cA], bns[64 + cA], bns[cB], bns[64 + cB])
  }
  {
    const float a0 = cfW[cC], a1 = cfW[64 + cC], a2 = cfW[128 + cC], a3 = cfW[192 + cC];
    const float b0 = cfW[cD], b1 = cfW[64 + cD], b2 = cfW[128 + cD], b3 = cfW[192 + cD];
    L0T(0, tA0, tB0, a0, a1, a2, a3, b0, b1, b2, b3)
    L0T(1, tA1, tB1, a0, a1, a2, a3, b0, b1, b2, b3)
    L0T(2, tA2, tB2, a0, a1, a2, a3, b0, b1, b2, b3)
    L0T(3, tA3, tB3, a0, a1, a2, a3, b0, b1, b2, b3)
    L0T(4, tA4, tB4, a0, a1, a2, a3, b0, b1, b2, b3)
    EPILOG2(hC0, hC1, hC2, hC3, hC4, hD0, hD1, hD2, hD3, hD4, cqC, cqD, cC, cD,
            false, true, cfb[cC], cfb[cD], bns[cC], bns[64 + cC], bns[cD], bns[64 + cD])
  }
#undef L0T

  // ---- layers 1..6: read all A-frags, then two pair-phases (no barriers)
#pragma unroll 1
  for (int l = 1; l <= 6; ++l) {
    RD_A()
    LDB(l - 1, 0, 1)
    MFMA_PAIR()
    EPILOG2(hA0, hA1, hA2, hA3, hA4, hB0, hB1, hB2, hB3, hB4, cqA, cqB, cA, cB,
            true, true, cmb[(l - 1) * 64 + cA], cmb[(l - 1) * 64 + cB],
            bns[l * 128 + cA], bns[l * 128 + 64 + cA],
            bns[l * 128 + cB], bns[l * 128 + 64 + cB])
    LDB(l - 1, 2, 3)
    MFMA_PAIR()
    EPILOG2(hC0, hC1, hC2, hC3, hC4, hD0, hD1, hD2, hD3, hD4, cqC, cqD, cC, cD,
            true, true, cmb[(l - 1) * 64 + cC], cmb[(l - 1) * 64 + cD],
            bns[l * 128 + cC], bns[l * 128 + 64 + cC],
            bns[l * 128 + cD], bns[l * 128 + 64 + cD])
  }

  // ---- layer 7: no bn, no residual, no h-store
  {
    RD_A()
    LDB(6, 0, 1)
    MFMA_PAIR()
    EPILOG2(hA0, hA1, hA2, hA3, hA4, hB0, hB1, hB2, hB3, hB4, cqA, cqB, cA, cB,
            false, false, clb[cA], clb[cB], 1.f, 0.f, 1.f, 0.f)
    LDB(6, 2, 3)
    MFMA_PAIR()
    EPILOG2(hC0, hC1, hC2, hC3, hC4, hD0, hD1, hD2, hD3, hD4, cqC, cqD, cC, cD,
            false, false, clb[cC], clb[cD], 1.f, 0.f, 1.f, 0.f)
  }

  // ---- readout (per-wave, in-order LDS, still no barriers)
  RDOUT(hA0, hA1, hA2, hA3, hA4, cA)
  RDOUT(hB0, hB1, hB2, hB3, hB4, cB)
  RDOUT(hC0, hC1, hC2, hC3, hC4, cC)
  RDOUT(hD0, hD1, hD2, hD3, hD4, cD)

  // attention gate: all 64 lanes, f = lane
  {
    float z = 0.f;
#pragma unroll 4
    for (int k = 0; k < 64; ++k) z = fmaf(mrow[k], aW1[k * 64 + lane], z);
    z = fmaxf(z + ab1[lane], 0.f);
    float pr = z * aW2[lane];
#pragma unroll
    for (int off = 32; off > 0; off >>= 1) pr += __shfl_xor(pr, off, 64);
    const float att = 1.f / (1.f + expf(-(pr + ab2[0])));
    gv[128 + lane] = mrow[lane] * att;
  }
  // fc1 + relu + fc2
  {
    float a = f1b[lane];
#pragma unroll 4
    for (int i = 0; i < 192; ++i) a = fmaf(gv[i], f1W[i * 64 + lane], a);
    const float y = fmaxf(a, 0.f);
    float po[7];
#pragma unroll
    for (int o = 0; o < 7; ++o) po[o] = y * f2W[lane * 7 + o];
#pragma unroll
    for (int o = 0; o < 7; ++o)
#pragma unroll
      for (int off = 32; off > 0; off >>= 1) po[o] += __shfl_xor(po[o], off, 64);
    if (lane == 0) {
#pragma unroll
      for (int o = 0; o < 7; ++o) out[(size_t)g * 7 + o] = po[o] + f2b[o];
    }
  }
}

extern "C" void kernel_launch(void* const* d_in, const int* in_sizes, int n_in,
                              void* d_out, int out_size, void* d_ws, size_t ws_size,
                              hipStream_t stream) {
  (void)in_sizes; (void)n_in; (void)ws_size;
  const float* x   = (const float*)d_in[0];
  const float* cfW = (const float*)d_in[4];
  const float* cfb = (const float*)d_in[5];
  const float* cmW = (const float*)d_in[6];
  const float* cmb = (const float*)d_in[7];
  const float* clW = (const float*)d_in[8];
  const float* clb = (const float*)d_in[9];
  const float* bng = (const float*)d_in[10];
  const float* bnb = (const float*)d_in[11];
  const float* bnm = (const float*)d_in[12];
  const float* bnv = (const float*)d_in[13];
  const float* aW1 = (const float*)d_in[14];
  const float* ab1 = (const float*)d_in[15];
  const float* aW2 = (const float*)d_in[16];
  const float* ab2 = (const float*)d_in[17];
  const float* f1W = (const float*)d_in[18];
  const float* f1b = (const float*)d_in[19];
  const float* f2W = (const float*)d_in[20];
  const float* f2b = (const float*)d_in[21];

  u16* frag = (u16*)d_ws;                      // 57344 B
  float* bns = (float*)((char*)d_ws + 57344);  // 7*128 floats
  const int ngraphs = out_size / 7;
  const int nblocks = (ngraphs + 3) / 4;

  prep<<<dim3(16), dim3(256), 0, stream>>>(cmW, clW, bng, bnb, bnm, bnv, frag, bns);
  gcn_fused<<<dim3(nblocks), dim3(256), 0, stream>>>(
      x, cfW, cfb, cmb, clb, aW1, ab1, aW2, ab2, f1W, f1b, f2W, f2b,
      frag, bns, (float*)d_out, ngraphs);
}

// Round 13
// 148.783 us; speedup vs baseline: 1.7815x; 1.7815x over previous
//
#include <hip/hip_runtime.h>

typedef float f32x4 __attribute__((ext_vector_type(4)));
typedef short short8 __attribute__((ext_vector_type(8)));
typedef unsigned int u32;
typedef unsigned short u16;

#define CLL 0.25f                     // landmark self/neighbor coeff (deg=4)
#define CML 0.06019292654288460f      // 0.5/sqrt(69)
#define SELFM 0.014492753623188406f   // 1/69

__device__ __forceinline__ u16 f2bf(float x) {
  u32 b = __float_as_uint(x);
  return (u16)((b + 0x7FFFu + ((b >> 16) & 1u)) >> 16);
}

__device__ __forceinline__ u32 cvtpk(float a, float b) {
  u32 r;
  asm("v_cvt_pk_bf16_f32 %0, %1, %2" : "=v"(r) : "v"(a), "v"(b));
  return r;
}

// prep: (a) swizzle 7 HIDxHID weight mats into bf16 MFMA B-fragments;
//       (b) fold BN into per-layer affine sc/sh.
__global__ void prep(const float* __restrict__ midW, const float* __restrict__ lastW,
                     const float* __restrict__ bng, const float* __restrict__ bnb,
                     const float* __restrict__ bnm, const float* __restrict__ bnv,
                     u16* __restrict__ frag, float* __restrict__ bns) {
  const int t0 = blockIdx.x * blockDim.x + threadIdx.x;
  for (int u = t0; u < 7 * 4 * 2 * 64; u += gridDim.x * blockDim.x) {
    const int lane = u & 63;
    const int t = u >> 6;
    const int ks = t & 1;
    const int nt = (t >> 1) & 3;
    const int l = t >> 3;  // 0..6 -> layers 1..7
    const float* W = (l < 6) ? (midW + l * 4096) : lastW;
    const int col = nt * 16 + (lane & 15);
    const int kb = ks * 32 + (lane >> 4) * 8;
    u16* dst = frag + (size_t)u * 8;
#pragma unroll
    for (int j = 0; j < 8; ++j) dst[j] = f2bf(W[(kb + j) * 64 + col]);
  }
  for (int u = t0; u < 7 * 64; u += gridDim.x * blockDim.x) {
    const int l = u >> 6, f = u & 63;
    const float sc = (float)((double)bng[l * 64 + f] / sqrt((double)bnv[l * 64 + f] + 1e-5));
    bns[l * 128 + f] = sc;
    bns[l * 128 + 64 + f] = bnb[l * 64 + f] - bnm[l * 64 + f] * sc;
  }
}

#define SUM4(V) ((V)[0] + (V)[1] + (V)[2] + (V)[3])
#define MAX4(V) fmaxf(fmaxf((V)[0], (V)[1]), fmaxf((V)[2], (V)[3]))

// write address (elems) for node n=16*MT+4*qg+R, col c, XOR-swizzled
#define WADDR(MT, R) ((16 * (MT) + 4 * qg + (R)) * 64 + (cq ^ ((R) << 3)))

// ring stencil for one 4-node run; H updated in place. All indices compile-time.
#define STEP(MT, T, TPM1, TNP1, H, RESID)                              \
  {                                                                    \
    const float sp = (qg == 3) ? TPM1[3] : T[3];                       \
    const float pv = __shfl(sp, (lane + 48) & 63, 64);                 \
    const float sn = (qg == 0) ? TNP1[0] : T[0];                       \
    const float nv = __shfl(sn, (lane + 16) & 63, 64);                 \
    const float ta0 = ((MT) == 0 && qg == 0) ? t4[3] : pv;             \
    const float tb3 = ((MT) == 4 && qg == 0) ? t0[0] : nv;             \
    float o0 = fmaf(CLL, ta0 + T[0] + T[1], cmt);                      \
    float o1 = fmaf(CLL, T[0] + T[1] + T[2], cmt);                     \
    float o2 = fmaf(CLL, T[1] + T[2] + T[3], cmt);                     \
    float o3 = fmaf(CLL, T[2] + T[3] + tb3, cmt);                      \
    o0 = fmaf(fmaxf(o0, 0.f), sc, sh);                                 \
    o1 = fmaf(fmaxf(o1, 0.f), sc, sh);                                 \
    o2 = fmaf(fmaxf(o2, 0.f), sc, sh);                                 \
    o3 = fmaf(fmaxf(o3, 0.f), sc, sh);                                 \
    if (RESID) { o0 += H[0]; o1 += H[1]; o2 += H[2]; o3 += H[3]; }     \
    H[0] = o0; H[1] = o1; H[2] = o2; H[3] = o3;                        \
  }

#define WPAIR(HW, MT, H)                                               \
  {                                                                    \
    const u32 pa = cvtpk(H[0], H[1]);                                  \
    const u32 pb = cvtpk(H[2], H[3]);                                  \
    (HW)[WADDR(MT, 0)] = (u16)pa;                                      \
    (HW)[WADDR(MT, 1)] = (u16)(pa >> 16);                              \
    (HW)[WADDR(MT, 2)] = (u16)pb;                                      \
    (HW)[WADDR(MT, 3)] = (u16)(pb >> 16);                              \
  }

// epilogue: master agg + stencil + bn/relu/resid in registers, then bf16 writes
#define EPILOG(RESID, WRITE, HBW)                                      \
  {                                                                    \
    float S = SUM4(t0) + SUM4(t1) + SUM4(t2) + SUM4(t3) + SUM4(t4);    \
    if (qg == 1) S -= t4[0]; /* exclude master t; pad rows are 0 */    \
    S += __shfl_xor(S, 16, 64);                                        \
    S += __shfl_xor(S, 32, 64);                                        \
    const float t68b = __shfl(t4[0], 16 + p15, 64);                    \
    const float cmt = fmaf(CML, t68b, bias);                           \
    float mv = fmaxf(fmaf(CML, S, fmaf(SELFM, t68b, bias)), 0.f);      \
    mv = fmaf(mv, sc, sh);                                             \
    if (RESID) mv += h4[0];                                            \
    STEP(0, t0, t4, t1, h0, RESID)                                     \
    STEP(1, t1, t0, t2, h1, RESID)                                     \
    STEP(2, t2, t1, t3, h2, RESID)                                     \
    STEP(3, t3, t2, t4, h3, RESID)                                     \
    STEP(4, t4, t3, t0, h4, RESID)                                     \
    if (qg == 1) h4[0] = mv; /* master h lives in slot [4][0] */       \
    if (WRITE) {                                                       \
      u16* hw_ = (HBW);                                                \
      WPAIR(hw_, 0, h0)                                                \
      WPAIR(hw_, 1, h1)                                                \
      WPAIR(hw_, 2, h2)                                                \
      WPAIR(hw_, 3, h3)                                                \
      if (qg == 0) { WPAIR(hw_, 4, h4) }                               \
      else if (qg == 1) hw_[68 * 64 + (c ^ 32)] = (u16)cvtpk(h4[0], h4[0]); \
    }                                                                  \
  }

#define MP(HR, MT, T)                                                  \
  {                                                                    \
    const short8 a0 = *(const short8*)&(HR)[(MT) * 1024 + ra0];        \
    const short8 a1 = *(const short8*)&(HR)[(MT) * 1024 + ra1];        \
    f32x4 acc = {0.f, 0.f, 0.f, 0.f};                                  \
    acc = __builtin_amdgcn_mfma_f32_16x16x32_bf16(a0, b0, acc, 0, 0, 0); \
    acc = __builtin_amdgcn_mfma_f32_16x16x32_bf16(a1, b1, acc, 0, 0, 0); \
    T = acc;                                                           \
  }

__launch_bounds__(256)
__global__ void gcn_fused(
    const float* __restrict__ x,
    const float* __restrict__ cfW, const float* __restrict__ cfb,
    const float* __restrict__ cmb, const float* __restrict__ clb,
    const float* __restrict__ aW1, const float* __restrict__ ab1,
    const float* __restrict__ aW2, const float* __restrict__ ab2,
    const float* __restrict__ f1W, const float* __restrict__ f1b,
    const float* __restrict__ f2W, const float* __restrict__ f2b,
    const u16* __restrict__ frag, const float* __restrict__ bns,
    float* __restrict__ out) {
  // LDS: 20480 + 1280 + 256 + 768 + 1024 = 23808 B
  __shared__ u16 hb[2][80 * 64];  // bf16 h double-buffer, rows 69..79 stay 0
  __shared__ float xl4[80 * 4];   // staged x, rows 69..79 = 0
  __shared__ float mrow[64];      // final master h
  __shared__ float gv[192];       // readout concat [mean|max|master*att]
  __shared__ float part[256];     // cross-wave partial buffer (att / fc1)

  const int tid = threadIdx.x;
  const int g = blockIdx.x;
  const int lane = tid & 63;
  const int wv = tid >> 6;
  const int p15 = lane & 15;
  const int qg = lane >> 4;
  const int c = wv * 16 + p15;            // this thread's feature column
  const int cq = c ^ ((qg & 1) << 5);     // write-swizzle base
  const int rsw = (p15 & 7) << 3;
  const int ra0 = (p15 * 64 + qg * 8) ^ rsw;        // A-frag kg=0 base
  const int ra1 = (p15 * 64 + 32 + qg * 8) ^ rsw;   // A-frag kg=1 base

  // ---- preload ALL per-layer scalars (hides global latency under staging)
  float lb[8], ls[8], lh[8];
  lb[0] = cfb[c]; ls[0] = bns[c]; lh[0] = bns[64 + c];
#pragma unroll
  for (int l = 1; l <= 6; ++l) {
    lb[l] = cmb[(l - 1) * 64 + c];
    ls[l] = bns[l * 128 + c];
    lh[l] = bns[l * 128 + 64 + c];
  }
  lb[7] = clb[c]; ls[7] = 1.f; lh[7] = 0.f;

  // prefetch layer-1 B fragments
  const u16* fb = frag + ((size_t)(0 * 4 + wv) * 2 * 64 + lane) * 8;
  short8 b0 = *(const short8*)fb;
  short8 b1 = *(const short8*)(fb + 512);

  // zero ONLY pad rows 69..79 of both hb buffers (data rows are fully
  // rewritten every layer; pads are never stored to) -> 704 u32 vs 5120
  {
    u32* hz = (u32*)hb;
#pragma unroll
    for (int it = 0; it < 2; ++it) {
      const int i = tid + it * 256;
      if (i < 352) {
        hz[2208 + i] = 0u;          // buf0 rows 69..79
        hz[2560 + 2208 + i] = 0u;   // buf1 rows 69..79
      }
    }
  }
  if (tid < 69)
    *(f32x4*)&xl4[tid * 4] = *(const f32x4*)&x[((size_t)g * 69 + tid) * 4];
  else if (tid < 80)
    *(f32x4*)&xl4[tid * 4] = (f32x4){0.f, 0.f, 0.f, 0.f};

  f32x4 t0, t1, t2, t3, t4;
  f32x4 h0, h1, h2, h3, h4;

  __syncthreads();

  // ---- layer 0: t = x @ W_first (exact fp32, K=4), nodes in MFMA layout
  {
    const float w0 = cfW[c], w1 = cfW[64 + c], w2 = cfW[128 + c], w3 = cfW[192 + c];
#define L0T(MT, T)                                                     \
    { _Pragma("unroll") for (int r = 0; r < 4; ++r) {                  \
        const f32x4 xv = *(const f32x4*)&xl4[(16 * (MT) + 4 * qg + r) * 4]; \
        T[r] = fmaf(xv[0], w0, fmaf(xv[1], w1, fmaf(xv[2], w2, xv[3] * w3))); } }
    L0T(0, t0) L0T(1, t1) L0T(2, t2) L0T(3, t3) L0T(4, t4)
#undef L0T
  }
  {
    const float bias = lb[0], sc = ls[0], sh = lh[0];
    EPILOG(false, true, &hb[0][0])
  }
  __syncthreads();

  // ---- layers 1..6: MFMA + register epilogue (bn + residual)
#pragma unroll
  for (int l = 1; l <= 6; ++l) {
    const u16* fbn = frag + ((size_t)(l * 4 + wv) * 2 * 64 + lane) * 8;
    const short8 nb0 = *(const short8*)fbn;
    const short8 nb1 = *(const short8*)(fbn + 512);
    const u16* hr = &hb[(l + 1) & 1][0];
    __builtin_amdgcn_s_setprio(1);
    MP(hr, 0, t0) MP(hr, 1, t1) MP(hr, 2, t2) MP(hr, 3, t3) MP(hr, 4, t4)
    __builtin_amdgcn_s_setprio(0);
    b0 = nb0;
    b1 = nb1;
    const float bias = lb[l], sc = ls[l], sh = lh[l];
    EPILOG(true, true, &hb[l & 1][0])
    __syncthreads();
  }

  // ---- layer 7: MFMA + epilogue (no bn, no residual, no hb write)
  {
    const u16* hr = &hb[0][0];
    __builtin_amdgcn_s_setprio(1);
    MP(hr, 0, t0) MP(hr, 1, t1) MP(hr, 2, t2) MP(hr, 3, t3) MP(hr, 4, t4)
    __builtin_amdgcn_s_setprio(0);
    const float bias = lb[7], sc = ls[7], sh = lh[7];
    EPILOG(false, false, (u16*)nullptr)
  }

  // ---- readout: per-col landmark mean/max from registers
  {
    float s = SUM4(h0) + SUM4(h1) + SUM4(h2) + SUM4(h3);
    float mx = fmaxf(fmaxf(MAX4(h0), MAX4(h1)), fmaxf(MAX4(h2), MAX4(h3)));
    if (qg == 0) {  // only qg==0's mt=4 run (nodes 64..67) is valid landmarks
      s += SUM4(h4);
      mx = fmaxf(mx, MAX4(h4));
    }
    s += __shfl_xor(s, 16, 64);
    s += __shfl_xor(s, 32, 64);
    mx = fmaxf(mx, __shfl_xor(mx, 16, 64));
    mx = fmaxf(mx, __shfl_xor(mx, 32, 64));
    if (qg == 0) {
      gv[c] = s * (1.f / 68.f);
      gv[64 + c] = mx;
    }
    if (qg == 1) mrow[c] = h4[0];
  }
  __syncthreads();

  // ---- attention gate (distributed over all 4 waves)
  {
    float z = 0.f;
#pragma unroll
    for (int k = 0; k < 16; ++k)
      z = fmaf(mrow[wv * 16 + k], aW1[(wv * 16 + k) * 64 + lane], z);
    part[wv * 64 + lane] = z;
  }
  __syncthreads();
  if (tid < 64) {
    float z = part[tid] + part[64 + tid] + part[128 + tid] + part[192 + tid] + ab1[tid];
    z = fmaxf(z, 0.f);
    float pr = z * aW2[tid];
#pragma unroll
    for (int off = 32; off > 0; off >>= 1) pr += __shfl_xor(pr, off, 64);
    const float att = 1.f / (1.f + expf(-(pr + ab2[0])));
    gv[128 + tid] = mrow[tid] * att;
  }
  __syncthreads();

  // ---- fc1 partials (distributed over all 4 waves)
  {
    float a = 0.f;
#pragma unroll
    for (int i = 0; i < 48; ++i)
      a = fmaf(gv[wv * 48 + i], f1W[(wv * 48 + i) * 64 + lane], a);
    part[wv * 64 + lane] = a;
  }
  __syncthreads();
  if (tid < 64) {
    float a = part[tid] + part[64 + tid] + part[128 + tid] + part[192 + tid] + f1b[tid];
    const float y = fmaxf(a, 0.f);
    float po[7];
#pragma unroll
    for (int o = 0; o < 7; ++o) po[o] = y * f2W[tid * 7 + o];
#pragma unroll
    for (int o = 0; o < 7; ++o)
#pragma unroll
      for (int off = 32; off > 0; off >>= 1) po[o] += __shfl_xor(po[o], off, 64);
    if (tid == 0) {
#pragma unroll
      for (int o = 0; o < 7; ++o) out[(size_t)g * 7 + o] = po[o] + f2b[o];
    }
  }
}

extern "C" void kernel_launch(void* const* d_in, const int* in_sizes, int n_in,
                              void* d_out, int out_size, void* d_ws, size_t ws_size,
                              hipStream_t stream) {
  (void)in_sizes; (void)n_in; (void)ws_size;
  const float* x   = (const float*)d_in[0];
  const float* cfW = (const float*)d_in[4];
  const float* cfb = (const float*)d_in[5];
  const float* cmW = (const float*)d_in[6];
  const float* cmb = (const float*)d_in[7];
  const float* clW = (const float*)d_in[8];
  const float* clb = (const float*)d_in[9];
  const float* bng = (const float*)d_in[10];
  const float* bnb = (const float*)d_in[11];
  const float* bnm = (const float*)d_in[12];
  const float* bnv = (const float*)d_in[13];
  const float* aW1 = (const float*)d_in[14];
  const float* ab1 = (const float*)d_in[15];
  const float* aW2 = (const float*)d_in[16];
  const float* ab2 = (const float*)d_in[17];
  const float* f1W = (const float*)d_in[18];
  const float* f1b = (const float*)d_in[19];
  const float* f2W = (const float*)d_in[20];
  const float* f2b = (const float*)d_in[21];

  u16* frag = (u16*)d_ws;                      // 57344 B
  float* bns = (float*)((char*)d_ws + 57344);  // 7*128 floats
  const int ngraphs = out_size / 7;

  prep<<<dim3(16), dim3(256), 0, stream>>>(cmW, clW, bng, bnb, bnm, bnv, frag, bns);
  gcn_fused<<<dim3(ngraphs), dim3(256), 0, stream>>>(
      x, cfW, cfb, cmb, clb, aW1, ab1, aW2, ab2, f1W, f1b, f2W, f2b,
      frag, bns, (float*)d_out);
}

// Round 14
// 148.059 us; speedup vs baseline: 1.7902x; 1.0049x over previous
//
#include <hip/hip_runtime.h>

typedef float f32x4 __attribute__((ext_vector_type(4)));
typedef short short8 __attribute__((ext_vector_type(8)));
typedef unsigned int u32;
typedef unsigned short u16;

#define CLL 0.25f                     // landmark self/neighbor coeff (deg=4)
#define CML 0.06019292654288460f      // 0.5/sqrt(69)
#define SELFM 0.014492753623188406f   // 1/69

__device__ __forceinline__ u16 f2bf(float x) {
  u32 b = __float_as_uint(x);
  return (u16)((b + 0x7FFFu + ((b >> 16) & 1u)) >> 16);
}

__device__ __forceinline__ u32 cvtpk(float a, float b) {
  u32 r;
  asm("v_cvt_pk_bf16_f32 %0, %1, %2" : "=v"(r) : "v"(a), "v"(b));
  return r;
}

// prep: (a) swizzle 7 HIDxHID weight mats into bf16 MFMA B-fragments;
//       (b) fold BN into per-layer affine sc/sh.
__global__ void prep(const float* __restrict__ midW, const float* __restrict__ lastW,
                     const float* __restrict__ bng, const float* __restrict__ bnb,
                     const float* __restrict__ bnm, const float* __restrict__ bnv,
                     u16* __restrict__ frag, float* __restrict__ bns) {
  const int t0 = blockIdx.x * blockDim.x + threadIdx.x;
  for (int u = t0; u < 7 * 4 * 2 * 64; u += gridDim.x * blockDim.x) {
    const int lane = u & 63;
    const int t = u >> 6;
    const int ks = t & 1;
    const int nt = (t >> 1) & 3;
    const int l = t >> 3;  // 0..6 -> layers 1..7
    const float* W = (l < 6) ? (midW + l * 4096) : lastW;
    const int col = nt * 16 + (lane & 15);
    const int kb = ks * 32 + (lane >> 4) * 8;
    u16* dst = frag + (size_t)u * 8;
#pragma unroll
    for (int j = 0; j < 8; ++j) dst[j] = f2bf(W[(kb + j) * 64 + col]);
  }
  for (int u = t0; u < 7 * 64; u += gridDim.x * blockDim.x) {
    const int l = u >> 6, f = u & 63;
    const float sc = (float)((double)bng[l * 64 + f] / sqrt((double)bnv[l * 64 + f] + 1e-5));
    bns[l * 128 + f] = sc;
    bns[l * 128 + 64 + f] = bnb[l * 64 + f] - bnm[l * 64 + f] * sc;
  }
}

#define SUM4(V) ((V)[0] + (V)[1] + (V)[2] + (V)[3])
#define MAX4(V) fmaxf(fmaxf((V)[0], (V)[1]), fmaxf((V)[2], (V)[3]))

// write address (elems) for node n=16*MT+4*qg+R, col c, XOR-swizzled
#define WADDR(MT, R) ((16 * (MT) + 4 * qg + (R)) * 64 + (cq ^ ((R) << 3)))

// ring stencil for one 4-node run; H updated in place. All indices compile-time.
#define STEP(MT, T, TPM1, TNP1, H, RESID)                              \
  {                                                                    \
    const float sp = (qg == 3) ? TPM1[3] : T[3];                       \
    const float pv = __shfl(sp, (lane + 48) & 63, 64);                 \
    const float sn = (qg == 0) ? TNP1[0] : T[0];                       \
    const float nv = __shfl(sn, (lane + 16) & 63, 64);                 \
    const float ta0 = ((MT) == 0 && qg == 0) ? t4[3] : pv;             \
    const float tb3 = ((MT) == 4 && qg == 0) ? t0[0] : nv;             \
    float o0 = fmaf(CLL, ta0 + T[0] + T[1], cmt);                      \
    float o1 = fmaf(CLL, T[0] + T[1] + T[2], cmt);                     \
    float o2 = fmaf(CLL, T[1] + T[2] + T[3], cmt);                     \
    float o3 = fmaf(CLL, T[2] + T[3] + tb3, cmt);                      \
    o0 = fmaf(fmaxf(o0, 0.f), sc, sh);                                 \
    o1 = fmaf(fmaxf(o1, 0.f), sc, sh);                                 \
    o2 = fmaf(fmaxf(o2, 0.f), sc, sh);                                 \
    o3 = fmaf(fmaxf(o3, 0.f), sc, sh);                                 \
    if (RESID) { o0 += H[0]; o1 += H[1]; o2 += H[2]; o3 += H[3]; }     \
    H[0] = o0; H[1] = o1; H[2] = o2; H[3] = o3;                        \
  }

#define WPAIR(HW, MT, H)                                               \
  {                                                                    \
    const u32 pa = cvtpk(H[0], H[1]);                                  \
    const u32 pb = cvtpk(H[2], H[3]);                                  \
    (HW)[WADDR(MT, 0)] = (u16)pa;                                      \
    (HW)[WADDR(MT, 1)] = (u16)(pa >> 16);                              \
    (HW)[WADDR(MT, 2)] = (u16)pb;                                      \
    (HW)[WADDR(MT, 3)] = (u16)(pb >> 16);                              \
  }

// epilogue: master agg + stencil + bn/relu/resid in registers, then bf16 writes
#define EPILOG(RESID, WRITE, HBW)                                      \
  {                                                                    \
    float S = SUM4(t0) + SUM4(t1) + SUM4(t2) + SUM4(t3) + SUM4(t4);    \
    if (qg == 1) S -= t4[0]; /* exclude master t; pad rows are 0 */    \
    S += __shfl_xor(S, 16, 64);                                        \
    S += __shfl_xor(S, 32, 64);                                        \
    const float t68b = __shfl(t4[0], 16 + p15, 64);                    \
    const float cmt = fmaf(CML, t68b, bias);                           \
    float mv = fmaxf(fmaf(CML, S, fmaf(SELFM, t68b, bias)), 0.f);      \
    mv = fmaf(mv, sc, sh);                                             \
    if (RESID) mv += h4[0];                                            \
    STEP(0, t0, t4, t1, h0, RESID)                                     \
    STEP(1, t1, t0, t2, h1, RESID)                                     \
    STEP(2, t2, t1, t3, h2, RESID)                                     \
    STEP(3, t3, t2, t4, h3, RESID)                                     \
    STEP(4, t4, t3, t0, h4, RESID)                                     \
    if (qg == 1) h4[0] = mv; /* master h lives in slot [4][0] */       \
    if (WRITE) {                                                       \
      u16* hw_ = (HBW);                                                \
      WPAIR(hw_, 0, h0)                                                \
      WPAIR(hw_, 1, h1)                                                \
      WPAIR(hw_, 2, h2)                                                \
      WPAIR(hw_, 3, h3)                                                \
      if (qg == 0) { WPAIR(hw_, 4, h4) }                               \
      else if (qg == 1) hw_[68 * 64 + (c ^ 32)] = (u16)cvtpk(h4[0], h4[0]); \
    }                                                                  \
  }

#define MP(HR, MT, T)                                                  \
  {                                                                    \
    const short8 a0 = *(const short8*)&(HR)[(MT) * 1024 + ra0];        \
    const short8 a1 = *(const short8*)&(HR)[(MT) * 1024 + ra1];        \
    f32x4 acc = {0.f, 0.f, 0.f, 0.f};                                  \
    acc = __builtin_amdgcn_mfma_f32_16x16x32_bf16(a0, b0, acc, 0, 0, 0); \
    acc = __builtin_amdgcn_mfma_f32_16x16x32_bf16(a1, b1, acc, 0, 0, 0); \
    T = acc;                                                           \
  }

__launch_bounds__(256)
__global__ void gcn_fused(
    const float* __restrict__ x,
    const float* __restrict__ cfW, const float* __restrict__ cfb,
    const float* __restrict__ cmb, const float* __restrict__ clb,
    const float* __restrict__ aW1, const float* __restrict__ ab1,
    const float* __restrict__ aW2, const float* __restrict__ ab2,
    const float* __restrict__ f1W, const float* __restrict__ f1b,
    const float* __restrict__ f2W, const float* __restrict__ f2b,
    const u16* __restrict__ frag, const float* __restrict__ bns,
    float* __restrict__ out) {
  // LDS: 20480 + 1280 (xl4 ∪ part) + 256 + 768 = 22784 B -> 7 blocks/CU
  __shared__ u16 hb[2][80 * 64];  // bf16 h double-buffer, rows 69..79 stay 0
  __shared__ float xpart[320];    // xl4 (layer 0 only) ∪ part (tail only)
  __shared__ float mrow[64];      // final master h
  __shared__ float gv[192];       // readout concat [mean|max|master*att]

  float* xl4 = xpart;             // 320 floats
  float* part = xpart;            // 256 floats (first used after last layer)

  const int tid = threadIdx.x;
  const int g = blockIdx.x;
  const int lane = tid & 63;
  const int wv = tid >> 6;
  const int p15 = lane & 15;
  const int qg = lane >> 4;
  const int c = wv * 16 + p15;            // this thread's feature column
  const int cq = c ^ ((qg & 1) << 5);     // write-swizzle base
  const int rsw = (p15 & 7) << 3;
  const int ra0 = (p15 * 64 + qg * 8) ^ rsw;        // A-frag kg=0 base
  const int ra1 = (p15 * 64 + 32 + qg * 8) ^ rsw;   // A-frag kg=1 base

  // ---- preload ALL per-layer scalars (hides global latency under staging)
  float lb[8], ls[8], lh[8];
  lb[0] = cfb[c]; ls[0] = bns[c]; lh[0] = bns[64 + c];
#pragma unroll
  for (int l = 1; l <= 6; ++l) {
    lb[l] = cmb[(l - 1) * 64 + c];
    ls[l] = bns[l * 128 + c];
    lh[l] = bns[l * 128 + 64 + c];
  }
  lb[7] = clb[c]; ls[7] = 1.f; lh[7] = 0.f;

  // prefetch layer-1 B fragments
  const u16* fb = frag + ((size_t)(0 * 4 + wv) * 2 * 64 + lane) * 8;
  short8 b0 = *(const short8*)fb;
  short8 b1 = *(const short8*)(fb + 512);

  // zero ONLY pad rows 69..79 of both hb buffers (data rows are fully
  // rewritten every layer; pads are never stored to) -> 704 u32 vs 5120
  {
    u32* hz = (u32*)hb;
#pragma unroll
    for (int it = 0; it < 2; ++it) {
      const int i = tid + it * 256;
      if (i < 352) {
        hz[2208 + i] = 0u;          // buf0 rows 69..79
        hz[2560 + 2208 + i] = 0u;   // buf1 rows 69..79
      }
    }
  }
  if (tid < 69)
    *(f32x4*)&xl4[tid * 4] = *(const f32x4*)&x[((size_t)g * 69 + tid) * 4];
  else if (tid < 80)
    *(f32x4*)&xl4[tid * 4] = (f32x4){0.f, 0.f, 0.f, 0.f};

  f32x4 t0, t1, t2, t3, t4;
  f32x4 h0, h1, h2, h3, h4;

  __syncthreads();

  // ---- layer 0: t = x @ W_first (exact fp32, K=4), nodes in MFMA layout
  {
    const float w0 = cfW[c], w1 = cfW[64 + c], w2 = cfW[128 + c], w3 = cfW[192 + c];
#define L0T(MT, T)                                                     \
    { _Pragma("unroll") for (int r = 0; r < 4; ++r) {                  \
        const f32x4 xv = *(const f32x4*)&xl4[(16 * (MT) + 4 * qg + r) * 4]; \
        T[r] = fmaf(xv[0], w0, fmaf(xv[1], w1, fmaf(xv[2], w2, xv[3] * w3))); } }
    L0T(0, t0) L0T(1, t1) L0T(2, t2) L0T(3, t3) L0T(4, t4)
#undef L0T
  }
  {
    const float bias = lb[0], sc = ls[0], sh = lh[0];
    EPILOG(false, true, &hb[0][0])
  }
  __syncthreads();

  // ---- layers 1..6: MFMA + register epilogue (bn + residual)
#pragma unroll
  for (int l = 1; l <= 6; ++l) {
    const u16* fbn = frag + ((size_t)(l * 4 + wv) * 2 * 64 + lane) * 8;
    const short8 nb0 = *(const short8*)fbn;
    const short8 nb1 = *(const short8*)(fbn + 512);
    const u16* hr = &hb[(l + 1) & 1][0];
    __builtin_amdgcn_s_setprio(1);
    MP(hr, 0, t0) MP(hr, 1, t1) MP(hr, 2, t2) MP(hr, 3, t3) MP(hr, 4, t4)
    __builtin_amdgcn_s_setprio(0);
    b0 = nb0;
    b1 = nb1;
    const float bias = lb[l], sc = ls[l], sh = lh[l];
    EPILOG(true, true, &hb[l & 1][0])
    __syncthreads();
  }

  // ---- layer 7: MFMA + epilogue (no bn, no residual, no hb write)
  {
    const u16* hr = &hb[0][0];
    __builtin_amdgcn_s_setprio(1);
    MP(hr, 0, t0) MP(hr, 1, t1) MP(hr, 2, t2) MP(hr, 3, t3) MP(hr, 4, t4)
    __builtin_amdgcn_s_setprio(0);
    const float bias = lb[7], sc = ls[7], sh = lh[7];
    EPILOG(false, false, (u16*)nullptr)
  }

  // ---- readout: per-col landmark mean/max from registers
  {
    float s = SUM4(h0) + SUM4(h1) + SUM4(h2) + SUM4(h3);
    float mx = fmaxf(fmaxf(MAX4(h0), MAX4(h1)), fmaxf(MAX4(h2), MAX4(h3)));
    if (qg == 0) {  // only qg==0's mt=4 run (nodes 64..67) is valid landmarks
      s += SUM4(h4);
      mx = fmaxf(mx, MAX4(h4));
    }
    s += __shfl_xor(s, 16, 64);
    s += __shfl_xor(s, 32, 64);
    mx = fmaxf(mx, __shfl_xor(mx, 16, 64));
    mx = fmaxf(mx, __shfl_xor(mx, 32, 64));
    if (qg == 0) {
      gv[c] = s * (1.f / 68.f);
      gv[64 + c] = mx;
    }
    if (qg == 1) mrow[c] = h4[0];
  }
  __syncthreads();  // also fences xl4 -> part reuse

  // ---- attention gate (distributed over all 4 waves)
  {
    float z = 0.f;
#pragma unroll
    for (int k = 0; k < 16; ++k)
      z = fmaf(mrow[wv * 16 + k], aW1[(wv * 16 + k) * 64 + lane], z);
    part[wv * 64 + lane] = z;
  }
  __syncthreads();
  if (tid < 64) {
    float z = part[tid] + part[64 + tid] + part[128 + tid] + part[192 + tid] + ab1[tid];
    z = fmaxf(z, 0.f);
    float pr = z * aW2[tid];
#pragma unroll
    for (int off = 32; off > 0; off >>= 1) pr += __shfl_xor(pr, off, 64);
    const float att = 1.f / (1.f + expf(-(pr + ab2[0])));
    gv[128 + tid] = mrow[tid] * att;
  }
  __syncthreads();

  // ---- fc1 partials (distributed over all 4 waves)
  {
    float a = 0.f;
#pragma unroll
    for (int i = 0; i < 48; ++i)
      a = fmaf(gv[wv * 48 + i], f1W[(wv * 48 + i) * 64 + lane], a);
    part[wv * 64 + lane] = a;
  }
  __syncthreads();
  if (tid < 64) {
    float a = part[tid] + part[64 + tid] + part[128 + tid] + part[192 + tid] + f1b[tid];
    const float y = fmaxf(a, 0.f);
    float po[7];
#pragma unroll
    for (int o = 0; o < 7; ++o) po[o] = y * f2W[tid * 7 + o];
#pragma unroll
    for (int o = 0; o < 7; ++o)
#pragma unroll
      for (int off = 32; off > 0; off >>= 1) po[o] += __shfl_xor(po[o], off, 64);
    if (tid == 0) {
#pragma unroll
      for (int o = 0; o < 7; ++o) out[(size_t)g * 7 + o] = po[o] + f2b[o];
    }
  }
}

extern "C" void kernel_launch(void* const* d_in, const int* in_sizes, int n_in,
                              void* d_out, int out_size, void* d_ws, size_t ws_size,
                              hipStream_t stream) {
  (void)in_sizes; (void)n_in; (void)ws_size;
  const float* x   = (const float*)d_in[0];
  const float* cfW = (const float*)d_in[4];
  const float* cfb = (const float*)d_in[5];
  const float* cmW = (const float*)d_in[6];
  const float* cmb = (const float*)d_in[7];
  const float* clW = (const float*)d_in[8];
  const float* clb = (const float*)d_in[9];
  const float* bng = (const float*)d_in[10];
  const float* bnb = (const float*)d_in[11];
  const float* bnm = (const float*)d_in[12];
  const float* bnv = (const float*)d_in[13];
  const float* aW1 = (const float*)d_in[14];
  const float* ab1 = (const float*)d_in[15];
  const float* aW2 = (const float*)d_in[16];
  const float* ab2 = (const float*)d_in[17];
  const float* f1W = (const float*)d_in[18];
  const float* f1b = (const float*)d_in[19];
  const float* f2W = (const float*)d_in[20];
  const float* f2b = (const float*)d_in[21];

  u16* frag = (u16*)d_ws;                      // 57344 B
  float* bns = (float*)((char*)d_ws + 57344);  // 7*128 floats
  const int ngraphs = out_size / 7;

  prep<<<dim3(16), dim3(256), 0, stream>>>(cmW, clW, bng, bnb, bnm, bnv, frag, bns);
  gcn_fused<<<dim3(ngraphs), dim3(256), 0, stream>>>(
      x, cfW, cfb, cmb, clb, aW1, ab1, aW2, ab2, f1W, f1b, f2W, f2b,
      frag, bns, (float*)d_out);
}